// Round 17
// baseline (183.378 us; speedup 1.0000x reference)
//
#include <hip/hip_runtime.h>
#include <hip/hip_fp16.h>

// ---------------------------------------------------------------------------
// 2-layer GCN on MI355X.
//   GCNConv(x) = A_hat (x W) + b = (A_hat x) W + b, and emb[labels]@W1 =
//   (emb@W1)[labels]. Per-label fp8 table temb8 expanded once to per-node
//   tembN (6.4MB) -> no label indirection in the edge path.
// CSR build (zero global atomics): K1 hist (+fused fp8 temb) / K2 colscan /
// K2b ebase / K3 scatter / K4 bsort (+dinv fold) -> packed 4B records
// csrE = src<<16 | fp16(w); dinv[src] applied in the aggs' batch phase.
// Aggs: QUARTER-WAVE gather -- fp8 rows are 128B so 16 lanes x uint2 cover a
// row; 4 edges per wave-instruction (one bpermute-shfl per 4 edges), float2
// accumulators (v_pk_fma_f32), next-batch prefetch. ~3.8 instr/edge vs 5.5
// for pair-gather; 2x edges in flight. (Aggs are issue-rate bound post-fp8:
// R14 proved bytes/row was the fabric lever; instr/edge is the issue lever.)
// R9/R11 lessons: register gather + high occupancy; no LDS staging.
// ---------------------------------------------------------------------------

#define CHUNKS 256  // chunk = ceil(e/256) = 6250 for e=1.6M
#define BSTAGE 2816 // bucket stage entries (avg bucket = 2048)

typedef float floatx2 __attribute__((ext_vector_type(2)));
__device__ __forceinline__ floatx2 splat2(float v) { return (floatx2){v, v}; }

// K1: blocks [0,bact): per-chunk histogram of dst-buckets.
//     blocks [bact, ...): temb8 = fp8(64 * emb @ W1), 32 rows/block.
__global__ __launch_bounds__(1024) void hist_temb_kernel(
    const int* __restrict__ dst, int* __restrict__ hist, int e, int chunk,
    int nb, int bact, const float* __restrict__ emb,
    const float* __restrict__ W1, unsigned* __restrict__ temb8, int vocab) {
  __shared__ unsigned lh[1024];
  __shared__ float xs[32][128];
  int b = blockIdx.x, t = threadIdx.x;
  if (b < bact) {
    lh[t] = 0;
    __syncthreads();
    int start = b * chunk, end = min(e, start + chunk);
    for (int i = start + t; i < end; i += 1024) atomicAdd(&lh[dst[i] >> 6], 1u);
    __syncthreads();
    if (t < nb) hist[(size_t)t * CHUNKS + b] = (int)lh[t];
  } else {
    int row = t >> 5, fl = t & 31;
    int r = (b - bact) * 32 + row;
    if (r < vocab)
      *(float4*)&xs[row][fl * 4] = *(const float4*)(emb + (size_t)r * 128 + fl * 4);
    __syncthreads();
    if (r < vocab) {
      float a0 = 0.f, a1 = 0.f, a2 = 0.f, a3 = 0.f;
#pragma unroll 4
      for (int k = 0; k < 128; ++k) {
        float xv = xs[row][k];
        float4 w4 = *(const float4*)(W1 + k * 128 + fl * 4);
        a0 = fmaf(xv, w4.x, a0); a1 = fmaf(xv, w4.y, a1);
        a2 = fmaf(xv, w4.z, a2); a3 = fmaf(xv, w4.w, a3);
      }
      int pk = __builtin_amdgcn_cvt_pk_fp8_f32(a0 * 64.f, a1 * 64.f, 0, false);
      pk = __builtin_amdgcn_cvt_pk_fp8_f32(a2 * 64.f, a3 * 64.f, pk, true);
      temb8[(size_t)r * 32 + fl] = (unsigned)pk;
    }
  }
}

// tembN[node][:] = temb8[labels[node]][:]  (per-node fp8 table, 6.4MB)
__global__ __launch_bounds__(256) void tembn_kernel(const int* __restrict__ labels,
                                                    const unsigned* __restrict__ temb8,
                                                    unsigned* __restrict__ tembN,
                                                    int n) {
  int i = blockIdx.x * 256 + threadIdx.x;
  int row = i >> 5, fl = i & 31;
  if (row < n) tembN[i] = temb8[(size_t)labels[row] * 32 + fl];
}

// K2: one wave per bucket k: exclusive scan of hist[k][*] over chunks.
__global__ __launch_bounds__(256) void colscan_kernel(const int* __restrict__ hist,
                                                      int* __restrict__ off,
                                                      int* __restrict__ tot,
                                                      int nb, int bact) {
  int k = (blockIdx.x * 256 + threadIdx.x) >> 6;
  int lane = threadIdx.x & 63;
  if (k >= nb) return;
  int carry = 0;
  for (int r = 0; r < CHUNKS / 64; ++r) {
    int b = r * 64 + lane;
    int h = (b < bact) ? hist[(size_t)k * CHUNKS + b] : 0;
    int x = h;
#pragma unroll
    for (int d = 1; d < 64; d <<= 1) {
      int tt = __shfl_up(x, d, 64);
      if (lane >= d) x += tt;
    }
    if (b < bact) off[(size_t)k * CHUNKS + b] = carry + x - h;
    carry += __shfl(x, 63, 64);
  }
  if (lane == 0) tot[k] = carry;
}

// K2b: single block: exclusive scan of tot[nb] -> ebase[nb+1].
__global__ __launch_bounds__(1024) void ebase_kernel(const int* __restrict__ tot,
                                                     int* __restrict__ ebase, int nb) {
  __shared__ int wsum[16];
  int t = threadIdx.x, lane = t & 63, wv = t >> 6;
  int v = (t < nb) ? tot[t] : 0;
  int x = v;
#pragma unroll
  for (int d = 1; d < 64; d <<= 1) {
    int tt = __shfl_up(x, d, 64);
    if (lane >= d) x += tt;
  }
  if (lane == 63) wsum[wv] = x;
  __syncthreads();
  int o = 0;
#pragma unroll
  for (int w = 0; w < 16; ++w) o += (w < wv) ? wsum[w] : 0;
  int excl = x - v + o;
  if (t < nb) ebase[t] = excl;
  if (t == nb - 1) ebase[nb] = excl + v;
}

// K3: scatter edges into bucket-grouped records (LDS rank, no global atomics).
// rec.x = src | dst_local<<16, rec.y = w bits.
__global__ __launch_bounds__(1024) void scatter_kernel(
    const int* __restrict__ src, const int* __restrict__ dst,
    const float* __restrict__ w, const int* __restrict__ off,
    const int* __restrict__ ebase, int2* __restrict__ brec, int e, int chunk,
    int nb) {
  __shared__ unsigned bincnt[1024];
  __shared__ int gbase[1024];
  int b = blockIdx.x, t = threadIdx.x;
  bincnt[t] = 0;
  if (t < nb) gbase[t] = ebase[t] + off[(size_t)t * CHUNKS + b];
  __syncthreads();
  int start = b * chunk, end = min(e, start + chunk);
  int s[7], d[7], ps[7];
  float wv[7];
#pragma unroll
  for (int u = 0; u < 7; ++u) {
    int i = start + u * 1024 + t;
    bool ok = i < end;
    s[u] = ok ? src[i] : 0;
    d[u] = ok ? dst[i] : 0;
    wv[u] = ok ? w[i] : 0.f;
  }
#pragma unroll
  for (int u = 0; u < 7; ++u) ps[u] = gbase[d[u] >> 6];
#pragma unroll
  for (int u = 0; u < 7; ++u) {
    int i = start + u * 1024 + t;
    if (i < end) {
      int k = d[u] >> 6;
      unsigned lr = atomicAdd(&bincnt[k], 1u);
      unsigned rx = (unsigned)s[u] | ((unsigned)(d[u] & 63) << 16);
      brec[ps[u] + (int)lr] = make_int2((int)rx, __float_as_int(wv[u]));
    }
  }
}

// K4: per-bucket 64-bin sort: brec -> csrE (src<<16 | fp16(w)), + rs[] + dinv.
__global__ __launch_bounds__(256) void bsort_kernel(const int2* __restrict__ brec,
                                                    const int* __restrict__ ebase,
                                                    unsigned* __restrict__ csrE,
                                                    int* __restrict__ rs,
                                                    float* __restrict__ dinv, int n) {
  __shared__ int2 stage[BSTAGE];
  __shared__ unsigned h64[2][64];
  __shared__ unsigned cur[2][64];
  __shared__ float rsum[2][64];
  int k = blockIdx.x, t = threadIdx.x;
  int p = t >> 7;
  int e0 = ebase[k], e1 = ebase[k + 1], cnt = e1 - e0;
  if (t < 128) { h64[t >> 6][t & 63] = 0; rsum[t >> 6][t & 63] = 0.f; }
  __syncthreads();
  bool fits = (cnt <= BSTAGE);
  for (int i = t; i < cnt; i += 256) {
    int2 r = brec[e0 + i];
    if (fits) stage[i] = r;
    unsigned dl = ((unsigned)r.x >> 16) & 63u;
    atomicAdd(&h64[p][dl], 1u);
    atomicAdd(&rsum[p][dl], __int_as_float(r.y));
  }
  __syncthreads();
  if (t < 64) {
    int h0 = (int)h64[0][t];
    int hv = h0 + (int)h64[1][t];
    int x = hv;
#pragma unroll
    for (int d = 1; d < 64; d <<= 1) {
      int tt = __shfl_up(x, d, 64);
      if (t >= d) x += tt;
    }
    int ex = x - hv;
    cur[0][t] = (unsigned)(e0 + ex);
    cur[1][t] = (unsigned)(e0 + ex + h0);
    int v = k * 64 + t;
    if (v <= n) rs[v] = e0 + ex;
    if (v < n) dinv[v] = rsqrtf(1.0f + rsum[0][t] + rsum[1][t]);
  }
  __syncthreads();
  for (int i = t; i < cnt; i += 256) {
    int2 r = fits ? stage[i] : brec[e0 + i];
    unsigned rx = (unsigned)r.x;
    int dl = (int)((rx >> 16) & 63u);
    int pos = (int)atomicAdd(&cur[p][dl], 1u);
    unsigned hb =
        (unsigned)__half_as_ushort(__float2half_rn(__int_as_float(r.y)));
    csrE[pos] = ((rx & 0xffffu) << 16) | hb;
  }
}

// Quarter-wave agg core (shared shape):
//   lane = q*16 + fl; q's edge index = j+q; fl owns features fl*8..fl*8+7.
//   Per iter: 1 shfl + 1 w-cvt + 1 uint2 load + 4 cvt_pk + 4 packed FMA
//   covers 4 edges. Batch phase: load 64 records, apply dinv[src], repack.

// Layer 1: out8 = fp8(64*relu(A_hat tembN + b1))
__global__ __launch_bounds__(256) void agg1_kernel(
    const int* __restrict__ rs, const unsigned* __restrict__ csrE,
    const float* __restrict__ dinv, const unsigned* __restrict__ tembN,
    const float* __restrict__ b1, unsigned* __restrict__ out8, int n) {
  int wid = (blockIdx.x * blockDim.x + threadIdx.x) >> 6;
  int lane = threadIdx.x & 63;
  if (wid >= n) return;
  int q = lane >> 4, fl = lane & 15;
  const char* tbp = (const char*)tembN + (fl << 3);
  float di = dinv[wid];
  floatx2 acc0 = {0.f, 0.f}, acc1 = {0.f, 0.f}, acc2 = {0.f, 0.f},
          acc3 = {0.f, 0.f};
  if (q == 0) {  // self term once
    uint2 r8 = *(const uint2*)(tbp + (((unsigned)wid) << 7));
    floatx2 d2 = splat2(di);
    acc0 = __builtin_amdgcn_cvt_pk_f32_fp8((int)r8.x, false) * d2;
    acc1 = __builtin_amdgcn_cvt_pk_f32_fp8((int)r8.x, true) * d2;
    acc2 = __builtin_amdgcn_cvt_pk_f32_fp8((int)r8.y, false) * d2;
    acc3 = __builtin_amdgcn_cvt_pk_f32_fp8((int)r8.y, true) * d2;
  }
  int base0 = rs[wid], r1v = rs[wid + 1];
  unsigned x = 0;  // packed record; 0 -> w=0 contributes nothing
  if (base0 + lane < r1v) {
    unsigned rec = csrE[base0 + lane];
    float wp = __half2float(__ushort_as_half((unsigned short)(rec & 0xffffu))) *
               dinv[rec >> 16];
    x = (rec & 0xffff0000u) | (unsigned)__half_as_ushort(__float2half_rn(wp));
  }
  for (int base = base0; base < r1v; base += 64) {
    unsigned nx = 0;
    if (base + 64 + lane < r1v) {
      unsigned rec = csrE[base + 64 + lane];
      float wp = __half2float(__ushort_as_half((unsigned short)(rec & 0xffffu))) *
                 dinv[rec >> 16];
      nx = (rec & 0xffff0000u) | (unsigned)__half_as_ushort(__float2half_rn(wp));
    }
    int nb = min(64, r1v - base);
#pragma unroll 4
    for (int j = 0; j < nb; j += 4) {
      unsigned xj = (unsigned)__shfl((int)x, j + q, 64);
      float vj = __half2float(__ushort_as_half((unsigned short)(xj & 0xffffu)));
      floatx2 v2 = splat2(vj);
      uint2 r8 = *(const uint2*)(tbp + ((xj >> 16) << 7));
      acc0 += __builtin_amdgcn_cvt_pk_f32_fp8((int)r8.x, false) * v2;
      acc1 += __builtin_amdgcn_cvt_pk_f32_fp8((int)r8.x, true) * v2;
      acc2 += __builtin_amdgcn_cvt_pk_f32_fp8((int)r8.y, false) * v2;
      acc3 += __builtin_amdgcn_cvt_pk_f32_fp8((int)r8.y, true) * v2;
    }
    x = nx;
  }
  // reduce across the 4 quarters (lanes 16 apart)
#pragma unroll
  for (int d = 16; d < 64; d <<= 1) {
    acc0[0] += __shfl_xor(acc0[0], d, 64); acc0[1] += __shfl_xor(acc0[1], d, 64);
    acc1[0] += __shfl_xor(acc1[0], d, 64); acc1[1] += __shfl_xor(acc1[1], d, 64);
    acc2[0] += __shfl_xor(acc2[0], d, 64); acc2[1] += __shfl_xor(acc2[1], d, 64);
    acc3[0] += __shfl_xor(acc3[0], d, 64); acc3[1] += __shfl_xor(acc3[1], d, 64);
  }
  if (q == 0) {
    float4 bA = ((const float4*)b1)[fl * 2];
    float4 bB = ((const float4*)b1)[fl * 2 + 1];
    // tembN is 64x true scale: relu(acc*di + 64*b) = 64*relu(true)
    float o0 = fmaxf(fmaf(acc0[0], di, bA.x * 64.f), 0.f);
    float o1 = fmaxf(fmaf(acc0[1], di, bA.y * 64.f), 0.f);
    float o2 = fmaxf(fmaf(acc1[0], di, bA.z * 64.f), 0.f);
    float o3 = fmaxf(fmaf(acc1[1], di, bA.w * 64.f), 0.f);
    float o4 = fmaxf(fmaf(acc2[0], di, bB.x * 64.f), 0.f);
    float o5 = fmaxf(fmaf(acc2[1], di, bB.y * 64.f), 0.f);
    float o6 = fmaxf(fmaf(acc3[0], di, bB.z * 64.f), 0.f);
    float o7 = fmaxf(fmaf(acc3[1], di, bB.w * 64.f), 0.f);
    int pk0 = __builtin_amdgcn_cvt_pk_fp8_f32(o0, o1, 0, false);
    pk0 = __builtin_amdgcn_cvt_pk_fp8_f32(o2, o3, pk0, true);
    int pk1 = __builtin_amdgcn_cvt_pk_fp8_f32(o4, o5, 0, false);
    pk1 = __builtin_amdgcn_cvt_pk_fp8_f32(o6, o7, pk1, true);
    *(uint2*)(out8 + (size_t)wid * 32 + fl * 2) =
        make_uint2((unsigned)pk0, (unsigned)pk1);
  }
}

// Layer 2 aggregation: out = A_hat h (fp8 source, f32 out).
__global__ __launch_bounds__(256) void agg2_kernel(
    const int* __restrict__ rs, const unsigned* __restrict__ csrE,
    const float* __restrict__ dinv, const unsigned* __restrict__ h8,
    float* __restrict__ out, int n) {
  int wid = (blockIdx.x * blockDim.x + threadIdx.x) >> 6;
  int lane = threadIdx.x & 63;
  if (wid >= n) return;
  int q = lane >> 4, fl = lane & 15;
  const char* hbp = (const char*)h8 + (fl << 3);
  float di = dinv[wid];
  floatx2 acc0 = {0.f, 0.f}, acc1 = {0.f, 0.f}, acc2 = {0.f, 0.f},
          acc3 = {0.f, 0.f};
  if (q == 0) {
    uint2 r8 = *(const uint2*)(hbp + (((unsigned)wid) << 7));
    floatx2 d2 = splat2(di);
    acc0 = __builtin_amdgcn_cvt_pk_f32_fp8((int)r8.x, false) * d2;
    acc1 = __builtin_amdgcn_cvt_pk_f32_fp8((int)r8.x, true) * d2;
    acc2 = __builtin_amdgcn_cvt_pk_f32_fp8((int)r8.y, false) * d2;
    acc3 = __builtin_amdgcn_cvt_pk_f32_fp8((int)r8.y, true) * d2;
  }
  int base0 = rs[wid], r1v = rs[wid + 1];
  unsigned x = 0;
  if (base0 + lane < r1v) {
    unsigned rec = csrE[base0 + lane];
    float wp = __half2float(__ushort_as_half((unsigned short)(rec & 0xffffu))) *
               dinv[rec >> 16];
    x = (rec & 0xffff0000u) | (unsigned)__half_as_ushort(__float2half_rn(wp));
  }
  for (int base = base0; base < r1v; base += 64) {
    unsigned nx = 0;
    if (base + 64 + lane < r1v) {
      unsigned rec = csrE[base + 64 + lane];
      float wp = __half2float(__ushort_as_half((unsigned short)(rec & 0xffffu))) *
                 dinv[rec >> 16];
      nx = (rec & 0xffff0000u) | (unsigned)__half_as_ushort(__float2half_rn(wp));
    }
    int nb = min(64, r1v - base);
#pragma unroll 4
    for (int j = 0; j < nb; j += 4) {
      unsigned xj = (unsigned)__shfl((int)x, j + q, 64);
      float vj = __half2float(__ushort_as_half((unsigned short)(xj & 0xffffu)));
      floatx2 v2 = splat2(vj);
      uint2 r8 = *(const uint2*)(hbp + ((xj >> 16) << 7));
      acc0 += __builtin_amdgcn_cvt_pk_f32_fp8((int)r8.x, false) * v2;
      acc1 += __builtin_amdgcn_cvt_pk_f32_fp8((int)r8.x, true) * v2;
      acc2 += __builtin_amdgcn_cvt_pk_f32_fp8((int)r8.y, false) * v2;
      acc3 += __builtin_amdgcn_cvt_pk_f32_fp8((int)r8.y, true) * v2;
    }
    x = nx;
  }
#pragma unroll
  for (int d = 16; d < 64; d <<= 1) {
    acc0[0] += __shfl_xor(acc0[0], d, 64); acc0[1] += __shfl_xor(acc0[1], d, 64);
    acc1[0] += __shfl_xor(acc1[0], d, 64); acc1[1] += __shfl_xor(acc1[1], d, 64);
    acc2[0] += __shfl_xor(acc2[0], d, 64); acc2[1] += __shfl_xor(acc2[1], d, 64);
    acc3[0] += __shfl_xor(acc3[0], d, 64); acc3[1] += __shfl_xor(acc3[1], d, 64);
  }
  if (q == 0) {
    float sc = di * 0.015625f;  // /64 de-scale
    float* rowp = out + (size_t)wid * 128 + fl * 8;
    *(float4*)rowp = make_float4(acc0[0] * sc, acc0[1] * sc, acc1[0] * sc,
                                 acc1[1] * sc);
    *(float4*)(rowp + 4) = make_float4(acc2[0] * sc, acc2[1] * sc,
                                       acc3[0] * sc, acc3[1] * sc);
  }
}

// In-place: y[rb..rb+31] = y[rb..rb+31] @ W + b.
__global__ __launch_bounds__(256) void gemm_bias_kernel(float* __restrict__ y,
                                                        const float* __restrict__ W,
                                                        const float* __restrict__ bias,
                                                        int n) {
  __shared__ float xs[32][128];
  int tid = threadIdx.x;
  int tc = tid & 31;
  int tr = tid >> 5;
  int rb = blockIdx.x * 32;
  {
    const float4* xg = (const float4*)(y + (size_t)rb * 128);
    float4* xls = (float4*)&xs[0][0];
#pragma unroll
    for (int i = 0; i < 4; ++i) {
      int idx = tid + i * 256;
      int row = rb + (idx >> 5);
      float4 val = (row < n) ? xg[idx] : make_float4(0.f, 0.f, 0.f, 0.f);
      xls[idx] = val;
    }
  }
  __syncthreads();
  int j0 = tc * 4;
  float4 b4 = *(const float4*)(bias + j0);
  float acc[4][4];
#pragma unroll
  for (int r = 0; r < 4; ++r) {
    acc[r][0] = b4.x; acc[r][1] = b4.y; acc[r][2] = b4.z; acc[r][3] = b4.w;
  }
#pragma unroll 4
  for (int k = 0; k < 128; ++k) {
    float4 w4 = *(const float4*)(W + k * 128 + j0);
#pragma unroll
    for (int r = 0; r < 4; ++r) {
      float xv = xs[tr * 4 + r][k];
      acc[r][0] = fmaf(xv, w4.x, acc[r][0]);
      acc[r][1] = fmaf(xv, w4.y, acc[r][1]);
      acc[r][2] = fmaf(xv, w4.z, acc[r][2]);
      acc[r][3] = fmaf(xv, w4.w, acc[r][3]);
    }
  }
#pragma unroll
  for (int r = 0; r < 4; ++r) {
    int row = rb + tr * 4 + r;
    if (row < n)
      *(float4*)(y + (size_t)row * 128 + j0) =
          make_float4(acc[r][0], acc[r][1], acc[r][2], acc[r][3]);
  }
}

extern "C" void kernel_launch(void* const* d_in, const int* in_sizes, int n_in,
                              void* d_out, int out_size, void* d_ws, size_t ws_size,
                              hipStream_t stream) {
  const int* labels = (const int*)d_in[0];
  const int* edge_index = (const int*)d_in[1];
  const float* weight = (const float*)d_in[2];
  const float* emb = (const float*)d_in[3];
  const float* W1 = (const float*)d_in[4];
  const float* b1 = (const float*)d_in[5];
  const float* W2 = (const float*)d_in[6];
  const float* b2 = (const float*)d_in[7];

  int n = in_sizes[0];
  int e = in_sizes[1] / 2;
  int vocab = in_sizes[3] / 128;
  const int* srcp = edge_index;
  const int* dstp = edge_index + e;

  int nb = (n + 63) >> 6;                 // dst buckets (782)
  int chunk = (e + CHUNKS - 1) / CHUNKS;  // 6250
  int bact = (e + chunk - 1) / chunk;
  int tblocks = (vocab + 31) / 32;        // temb blocks (32)

  float* ws = (float*)d_ws;
  size_t o = 0;
  auto alloc_f = [&](size_t c) { float* p = ws + o; o += (c + 255) & ~(size_t)255; return p; };
  int*      hist  = (int*)alloc_f((size_t)nb * CHUNKS);
  int*      off   = (int*)alloc_f((size_t)nb * CHUNKS);
  int*      tot   = (int*)alloc_f(nb);
  int*      ebase = (int*)alloc_f(nb + 1);
  int2*     brec  = (int2*)alloc_f((size_t)e * 2);
  int*      rs    = (int*)alloc_f(n + 1);
  unsigned* csrE  = (unsigned*)alloc_f(e);
  float*    dinv  = alloc_f(n);
  unsigned* temb8 = (unsigned*)alloc_f((size_t)vocab * 32);  // vocab*128 fp8
  unsigned* tembN = (unsigned*)alloc_f((size_t)n * 32);      // n*128 fp8
  unsigned* out8  = (unsigned*)alloc_f((size_t)n * 32);      // n*128 fp8
  (void)ws_size;

  dim3 b256(256);
  dim3 b1024(1024);
  int gagg = (int)(((size_t)n * 64 + 255) / 256);

  hist_temb_kernel<<<bact + tblocks, b1024, 0, stream>>>(dstp, hist, e, chunk, nb,
                                                         bact, emb, W1, temb8, vocab);
  tembn_kernel<<<(n * 32 + 255) / 256, b256, 0, stream>>>(labels, temb8, tembN, n);
  colscan_kernel<<<(nb * 64 + 255) / 256, b256, 0, stream>>>(hist, off, tot, nb, bact);
  ebase_kernel<<<1, b1024, 0, stream>>>(tot, ebase, nb);
  scatter_kernel<<<bact, b1024, 0, stream>>>(srcp, dstp, weight, off, ebase, brec,
                                             e, chunk, nb);
  bsort_kernel<<<nb, b256, 0, stream>>>(brec, ebase, csrE, rs, dinv, n);
  // layer 1: out8 = fp8(64*relu(A_hat tembN + b1))
  agg1_kernel<<<gagg, b256, 0, stream>>>(rs, csrE, dinv, tembN, b1, out8, n);
  // layer 2: d_out = (A_hat out1) @ W2 + b2   (agg first, then in-place GEMM)
  agg2_kernel<<<gagg, b256, 0, stream>>>(rs, csrE, dinv, out8, (float*)d_out, n);
  gemm_bias_kernel<<<(n + 31) / 32, b256, 0, stream>>>((float*)d_out, W2, b2, n);
}

// Round 18
// 165.561 us; speedup vs baseline: 1.1076x; 1.1076x over previous
//
#include <hip/hip_runtime.h>
#include <hip/hip_fp16.h>

// ---------------------------------------------------------------------------
// 2-layer GCN on MI355X.  (R18 = revert to R14, the measured best: 165.7us.)
//   GCNConv(x) = A_hat (x W) + b = (A_hat x) W + b, and emb[labels]@W1 =
//   (emb@W1)[labels] -> layer 1 gathers from a 256KB fp16 L2-resident
//   PER-LABEL table (R17 lesson: expanding to a 6.4MB per-node table
//   destroys agg1's L2 locality -- FETCH 10MB -> 56MB); layer 2 aggregates
//   first, then in-place GEMM on d_out.
// CSR build (zero global atomics): K1 hist (+fused temb) / K2 colscan /
// K2b ebase / K3 scatter (labels packed into csr.x) / K4 bsort (+dinv fold,
// 2-way split histograms).
// Aggs: pair-gather (2x32 lanes x 4 feats), batch-64 edge records,
// shfl-broadcast pairs with FIXED 16-step unrolls, next-batch prefetch,
// 32-bit byte-offset gathers, dinv[src] applied per-lane in batch phase.
// out1 stored FP8 E4M3 (x64 pre-scale): halves agg2's gather rows to 128B --
// agg2 is beyond-L2 random-fabric bound; bytes/row is its only lever (R14).
// R9/R11/R17 lessons: register pair-gather + high occupancy + small gather
// tables win; LDS staging, feature chunking, quarter-wave all regressed.
// ---------------------------------------------------------------------------

#define CHUNKS 256  // chunk = ceil(e/256) = 6250 for e=1.6M
#define BSTAGE 2816 // bucket stage entries (avg bucket = 2048)

typedef float floatx2 __attribute__((ext_vector_type(2)));

// K1: blocks [0,bact): per-chunk histogram of dst-buckets.
//     blocks [bact, bact+ceil(vocab/8)): temb = emb @ W1 (8 rows/block, fp16).
__global__ __launch_bounds__(1024) void hist_temb_kernel(
    const int* __restrict__ dst, int* __restrict__ hist, int e, int chunk,
    int nb, int bact, const float* __restrict__ emb,
    const float* __restrict__ W1, __half* __restrict__ temb, int vocab) {
  __shared__ unsigned lh[1024];
  __shared__ float xs[8][128];
  int b = blockIdx.x, t = threadIdx.x;
  if (b < bact) {
    lh[t] = 0;
    __syncthreads();
    int start = b * chunk, end = min(e, start + chunk);
    for (int i = start + t; i < end; i += 1024) atomicAdd(&lh[dst[i] >> 6], 1u);
    __syncthreads();
    if (t < nb) hist[(size_t)t * CHUNKS + b] = (int)lh[t];
  } else {
    int r = (b - bact) * 8 + (t >> 7);
    int j = t & 127;
    if (r < vocab) xs[t >> 7][j] = emb[r * 128 + j];
    __syncthreads();
    if (r < vocab) {
      float acc = 0.f;
#pragma unroll 8
      for (int k = 0; k < 128; ++k) acc = fmaf(xs[t >> 7][k], W1[k * 128 + j], acc);
      temb[r * 128 + j] = __float2half_rn(acc);
    }
  }
}

// K2: one wave per bucket k: exclusive scan of hist[k][*] over chunks.
__global__ __launch_bounds__(256) void colscan_kernel(const int* __restrict__ hist,
                                                      int* __restrict__ off,
                                                      int* __restrict__ tot,
                                                      int nb, int bact) {
  int k = (blockIdx.x * 256 + threadIdx.x) >> 6;
  int lane = threadIdx.x & 63;
  if (k >= nb) return;
  int carry = 0;
  for (int r = 0; r < CHUNKS / 64; ++r) {
    int b = r * 64 + lane;
    int h = (b < bact) ? hist[(size_t)k * CHUNKS + b] : 0;
    int x = h;
#pragma unroll
    for (int d = 1; d < 64; d <<= 1) {
      int tt = __shfl_up(x, d, 64);
      if (lane >= d) x += tt;
    }
    if (b < bact) off[(size_t)k * CHUNKS + b] = carry + x - h;
    carry += __shfl(x, 63, 64);
  }
  if (lane == 0) tot[k] = carry;
}

// K2b: single block: exclusive scan of tot[nb] -> ebase[nb+1].
__global__ __launch_bounds__(1024) void ebase_kernel(const int* __restrict__ tot,
                                                     int* __restrict__ ebase, int nb) {
  __shared__ int wsum[16];
  int t = threadIdx.x, lane = t & 63, wv = t >> 6;
  int v = (t < nb) ? tot[t] : 0;
  int x = v;
#pragma unroll
  for (int d = 1; d < 64; d <<= 1) {
    int tt = __shfl_up(x, d, 64);
    if (lane >= d) x += tt;
  }
  if (lane == 63) wsum[wv] = x;
  __syncthreads();
  int o = 0;
#pragma unroll
  for (int w = 0; w < 16; ++w) o += (w < wv) ? wsum[w] : 0;
  int excl = x - v + o;
  if (t < nb) ebase[t] = excl;
  if (t == nb - 1) ebase[nb] = excl + v;
}

// K3: scatter edges into bucket-grouped records (LDS rank, no global atomics).
__global__ __launch_bounds__(1024) void scatter_kernel(
    const int* __restrict__ src, const int* __restrict__ dst,
    const float* __restrict__ w, const int* __restrict__ labels,
    const int* __restrict__ off, const int* __restrict__ ebase,
    int2* __restrict__ brec, int e, int chunk, int nb) {
  __shared__ unsigned bincnt[1024];
  __shared__ int gbase[1024];
  int b = blockIdx.x, t = threadIdx.x;
  bincnt[t] = 0;
  if (t < nb) gbase[t] = ebase[t] + off[(size_t)t * CHUNKS + b];
  __syncthreads();
  int start = b * chunk, end = min(e, start + chunk);
  int s[7], d[7], lb[7], ps[7];
  float wv[7];
#pragma unroll
  for (int u = 0; u < 7; ++u) {
    int i = start + u * 1024 + t;
    bool ok = i < end;
    s[u] = ok ? src[i] : 0;
    d[u] = ok ? dst[i] : 0;
    wv[u] = ok ? w[i] : 0.f;
  }
#pragma unroll
  for (int u = 0; u < 7; ++u) lb[u] = labels[s[u]];
#pragma unroll
  for (int u = 0; u < 7; ++u) ps[u] = gbase[d[u] >> 6];
#pragma unroll
  for (int u = 0; u < 7; ++u) {
    int i = start + u * 1024 + t;
    if (i < end) {
      int k = d[u] >> 6;
      unsigned lr = atomicAdd(&bincnt[k], 1u);
      unsigned rx = (unsigned)s[u] | ((unsigned)(d[u] & 63) << 16) |
                    ((unsigned)lb[u] << 22);
      brec[ps[u] + (int)lr] = make_int2((int)rx, __float_as_int(wv[u]));
    }
  }
}

// K4: per-bucket 64-bin sort: brec -> csr (src|label<<16, w), + rs[] + dinv.
// 2-way split histograms/cursors halve same-address LDS atomic serialization.
__global__ __launch_bounds__(256) void bsort_kernel(const int2* __restrict__ brec,
                                                    const int* __restrict__ ebase,
                                                    int2* __restrict__ csr,
                                                    int* __restrict__ rs,
                                                    float* __restrict__ dinv, int n) {
  __shared__ int2 stage[BSTAGE];
  __shared__ unsigned h64[2][64];
  __shared__ unsigned cur[2][64];
  __shared__ float rsum[2][64];
  int k = blockIdx.x, t = threadIdx.x;
  int p = t >> 7;
  int e0 = ebase[k], e1 = ebase[k + 1], cnt = e1 - e0;
  if (t < 128) { h64[t >> 6][t & 63] = 0; rsum[t >> 6][t & 63] = 0.f; }
  __syncthreads();
  bool fits = (cnt <= BSTAGE);
  for (int i = t; i < cnt; i += 256) {
    int2 r = brec[e0 + i];
    if (fits) stage[i] = r;
    unsigned dl = ((unsigned)r.x >> 16) & 63u;
    atomicAdd(&h64[p][dl], 1u);
    atomicAdd(&rsum[p][dl], __int_as_float(r.y));
  }
  __syncthreads();
  if (t < 64) {
    int h0 = (int)h64[0][t];
    int hv = h0 + (int)h64[1][t];
    int x = hv;
#pragma unroll
    for (int d = 1; d < 64; d <<= 1) {
      int tt = __shfl_up(x, d, 64);
      if (t >= d) x += tt;
    }
    int ex = x - hv;
    cur[0][t] = (unsigned)(e0 + ex);
    cur[1][t] = (unsigned)(e0 + ex + h0);
    int v = k * 64 + t;
    if (v <= n) rs[v] = e0 + ex;
    if (v < n) dinv[v] = rsqrtf(1.0f + rsum[0][t] + rsum[1][t]);
  }
  __syncthreads();
  for (int i = t; i < cnt; i += 256) {
    int2 r = fits ? stage[i] : brec[e0 + i];
    unsigned rx = (unsigned)r.x;
    int dl = (int)((rx >> 16) & 63u);
    int pos = (int)atomicAdd(&cur[p][dl], 1u);
    csr[pos] = make_int2((int)((rx & 0xffffu) | ((rx >> 22) << 16)), r.y);
  }
}

// unpack 4 halves (loaded as float2, 8B) -> two float2
__device__ __forceinline__ void unpack4(float2 raw, float2& a, float2& b) {
  union { float f; __half2 h; } u0, u1;
  u0.f = raw.x;
  u1.f = raw.y;
  a = __half22float2(u0.h);
  b = __half22float2(u1.h);
}

// Layer 1: out8 = fp8(64*relu(A_hat temb[labels] + b1)); fp16 temb gathers.
// Pair-gather with next-batch prefetch; 32-bit byte-offset gathers.
__global__ __launch_bounds__(256) void agg1_kernel(
    const int* __restrict__ rs, const int2* __restrict__ csr,
    const float* __restrict__ dinv, const int* __restrict__ labels,
    const __half* __restrict__ temb, const float* __restrict__ b1,
    unsigned* __restrict__ out8, int n) {
  int wid = (blockIdx.x * blockDim.x + threadIdx.x) >> 6;
  int lane = threadIdx.x & 63;
  if (wid >= n) return;
  int half = lane >> 5, fl = lane & 31;
  unsigned flo = (unsigned)(fl << 3);
  const char* tb = (const char*)temb;
  float di = dinv[wid];
  float acc0, acc1, acc2, acc3;
  {
    unsigned off = ((unsigned)labels[wid] << 8) + flo;
    float2 raw = *(const float2*)(tb + off);
    float2 a, b;
    unpack4(raw, a, b);
    float ss = half ? 0.f : di;  // self term once (half 0 only)
    acc0 = a.x * ss; acc1 = a.y * ss; acc2 = b.x * ss; acc3 = b.y * ss;
  }
  int base0 = rs[wid], r1v = rs[wid + 1];
  int s = 0;
  float v = 0.f;
  if (base0 + lane < r1v) {
    int2 c = csr[base0 + lane];
    s = c.x;
    v = __int_as_float(c.y) * dinv[c.x & 0xffff];
  }
  for (int base = base0; base < r1v; base += 64) {
    int ns = 0;
    float nv = 0.f;
    if (base + 64 + lane < r1v) {
      int2 c = csr[base + 64 + lane];
      ns = c.x;
      nv = __int_as_float(c.y) * dinv[c.x & 0xffff];
    }
    int nb = min(64, r1v - base);
    int j = 0;
    for (; j + 16 <= nb; j += 16) {
#pragma unroll
      for (int u = 0; u < 8; ++u) {
        int jj = j + 2 * u + half;
        int sj = __shfl(s, jj, 64);
        float vj = __shfl(v, jj, 64);
        unsigned off = (((unsigned)sj >> 16) << 8) + flo;
        float2 raw = *(const float2*)(tb + off);
        float2 a, b;
        unpack4(raw, a, b);
        acc0 = fmaf(a.x, vj, acc0); acc1 = fmaf(a.y, vj, acc1);
        acc2 = fmaf(b.x, vj, acc2); acc3 = fmaf(b.y, vj, acc3);
      }
    }
    for (; j + 2 <= nb; j += 2) {
      int jj = j + half;
      int sj = __shfl(s, jj, 64);
      float vj = __shfl(v, jj, 64);
      unsigned off = (((unsigned)sj >> 16) << 8) + flo;
      float2 raw = *(const float2*)(tb + off);
      float2 a, b;
      unpack4(raw, a, b);
      acc0 = fmaf(a.x, vj, acc0); acc1 = fmaf(a.y, vj, acc1);
      acc2 = fmaf(b.x, vj, acc2); acc3 = fmaf(b.y, vj, acc3);
    }
    if (j < nb) {  // leftover single edge: half 1 contributes 0
      int sj = __shfl(s, j, 64);
      float vj0 = __shfl(v, j, 64);
      float vj = half ? 0.f : vj0;
      unsigned off = (((unsigned)sj >> 16) << 8) + flo;
      float2 raw = *(const float2*)(tb + off);
      float2 a, b;
      unpack4(raw, a, b);
      acc0 = fmaf(a.x, vj, acc0); acc1 = fmaf(a.y, vj, acc1);
      acc2 = fmaf(b.x, vj, acc2); acc3 = fmaf(b.y, vj, acc3);
    }
    s = ns;
    v = nv;
  }
  acc0 += __shfl_xor(acc0, 32, 64);
  acc1 += __shfl_xor(acc1, 32, 64);
  acc2 += __shfl_xor(acc2, 32, 64);
  acc3 += __shfl_xor(acc3, 32, 64);
  if (half == 0) {
    float4 b4 = ((const float4*)b1)[fl];
    acc0 = fmaxf(fmaf(acc0, di, b4.x), 0.f) * 64.f;
    acc1 = fmaxf(fmaf(acc1, di, b4.y), 0.f) * 64.f;
    acc2 = fmaxf(fmaf(acc2, di, b4.z), 0.f) * 64.f;
    acc3 = fmaxf(fmaf(acc3, di, b4.w), 0.f) * 64.f;
    int pk = __builtin_amdgcn_cvt_pk_fp8_f32(acc0, acc1, 0, false);
    pk = __builtin_amdgcn_cvt_pk_fp8_f32(acc2, acc3, pk, true);
    out8[(size_t)wid * 32 + fl] = (unsigned)pk;
  }
}

// Layer 2 aggregation: out = A_hat h (FP8 gather source, f32 output).
// Rows are 128B (32 lanes x 4B). Decode via v_cvt_pk_f32_fp8; final /64.
__global__ __launch_bounds__(256) void agg2_kernel(
    const int* __restrict__ rs, const int2* __restrict__ csr,
    const float* __restrict__ dinv, const unsigned* __restrict__ h8,
    float* __restrict__ out, int n) {
  int wid = (blockIdx.x * blockDim.x + threadIdx.x) >> 6;
  int lane = threadIdx.x & 63;
  if (wid >= n) return;
  int half = lane >> 5, fl = lane & 31;
  unsigned flo = (unsigned)(fl << 2);
  const char* hb = (const char*)h8;
  float di = dinv[wid];
  float acc0, acc1, acc2, acc3;
  {
    unsigned r8 = *(const unsigned*)(hb + ((unsigned)wid << 7) + flo);
    floatx2 a = __builtin_amdgcn_cvt_pk_f32_fp8((int)r8, false);
    floatx2 b = __builtin_amdgcn_cvt_pk_f32_fp8((int)r8, true);
    float ss = half ? 0.f : di;
    acc0 = a[0] * ss; acc1 = a[1] * ss; acc2 = b[0] * ss; acc3 = b[1] * ss;
  }
  int base0 = rs[wid], r1v = rs[wid + 1];
  int s = 0;
  float v = 0.f;
  if (base0 + lane < r1v) {
    int2 c = csr[base0 + lane];
    s = c.x;
    v = __int_as_float(c.y) * dinv[c.x & 0xffff];
  }
  for (int base = base0; base < r1v; base += 64) {
    int ns = 0;
    float nv = 0.f;
    if (base + 64 + lane < r1v) {
      int2 c = csr[base + 64 + lane];
      ns = c.x;
      nv = __int_as_float(c.y) * dinv[c.x & 0xffff];
    }
    int nb = min(64, r1v - base);
    int j = 0;
    for (; j + 16 <= nb; j += 16) {
#pragma unroll
      for (int u = 0; u < 8; ++u) {
        int jj = j + 2 * u + half;
        int sj = __shfl(s, jj, 64);
        float vj = __shfl(v, jj, 64);
        unsigned off = (((unsigned)sj & 0xffffu) << 7) + flo;
        unsigned r8 = *(const unsigned*)(hb + off);
        floatx2 a = __builtin_amdgcn_cvt_pk_f32_fp8((int)r8, false);
        floatx2 b = __builtin_amdgcn_cvt_pk_f32_fp8((int)r8, true);
        acc0 = fmaf(a[0], vj, acc0); acc1 = fmaf(a[1], vj, acc1);
        acc2 = fmaf(b[0], vj, acc2); acc3 = fmaf(b[1], vj, acc3);
      }
    }
    for (; j + 2 <= nb; j += 2) {
      int jj = j + half;
      int sj = __shfl(s, jj, 64);
      float vj = __shfl(v, jj, 64);
      unsigned off = (((unsigned)sj & 0xffffu) << 7) + flo;
      unsigned r8 = *(const unsigned*)(hb + off);
      floatx2 a = __builtin_amdgcn_cvt_pk_f32_fp8((int)r8, false);
      floatx2 b = __builtin_amdgcn_cvt_pk_f32_fp8((int)r8, true);
      acc0 = fmaf(a[0], vj, acc0); acc1 = fmaf(a[1], vj, acc1);
      acc2 = fmaf(b[0], vj, acc2); acc3 = fmaf(b[1], vj, acc3);
    }
    if (j < nb) {
      int sj = __shfl(s, j, 64);
      float vj0 = __shfl(v, j, 64);
      float vj = half ? 0.f : vj0;
      unsigned off = (((unsigned)sj & 0xffffu) << 7) + flo;
      unsigned r8 = *(const unsigned*)(hb + off);
      floatx2 a = __builtin_amdgcn_cvt_pk_f32_fp8((int)r8, false);
      floatx2 b = __builtin_amdgcn_cvt_pk_f32_fp8((int)r8, true);
      acc0 = fmaf(a[0], vj, acc0); acc1 = fmaf(a[1], vj, acc1);
      acc2 = fmaf(b[0], vj, acc2); acc3 = fmaf(b[1], vj, acc3);
    }
    s = ns;
    v = nv;
  }
  acc0 += __shfl_xor(acc0, 32, 64);
  acc1 += __shfl_xor(acc1, 32, 64);
  acc2 += __shfl_xor(acc2, 32, 64);
  acc3 += __shfl_xor(acc3, 32, 64);
  if (half == 0) {
    float sc = di * 0.015625f;  // /64 de-scale
    ((float4*)(out + (size_t)wid * 128))[fl] =
        make_float4(acc0 * sc, acc1 * sc, acc2 * sc, acc3 * sc);
  }
}

// In-place: y[rb..rb+31] = y[rb..rb+31] @ W + b.
__global__ __launch_bounds__(256) void gemm_bias_kernel(float* __restrict__ y,
                                                        const float* __restrict__ W,
                                                        const float* __restrict__ bias,
                                                        int n) {
  __shared__ float xs[32][128];
  int tid = threadIdx.x;
  int tc = tid & 31;
  int tr = tid >> 5;
  int rb = blockIdx.x * 32;
  {
    const float4* xg = (const float4*)(y + (size_t)rb * 128);
    float4* xls = (float4*)&xs[0][0];
#pragma unroll
    for (int i = 0; i < 4; ++i) {
      int idx = tid + i * 256;
      int row = rb + (idx >> 5);
      float4 val = (row < n) ? xg[idx] : make_float4(0.f, 0.f, 0.f, 0.f);
      xls[idx] = val;
    }
  }
  __syncthreads();
  int j0 = tc * 4;
  float4 b4 = *(const float4*)(bias + j0);
  float acc[4][4];
#pragma unroll
  for (int r = 0; r < 4; ++r) {
    acc[r][0] = b4.x; acc[r][1] = b4.y; acc[r][2] = b4.z; acc[r][3] = b4.w;
  }
#pragma unroll 4
  for (int k = 0; k < 128; ++k) {
    float4 w4 = *(const float4*)(W + k * 128 + j0);
#pragma unroll
    for (int r = 0; r < 4; ++r) {
      float xv = xs[tr * 4 + r][k];
      acc[r][0] = fmaf(xv, w4.x, acc[r][0]);
      acc[r][1] = fmaf(xv, w4.y, acc[r][1]);
      acc[r][2] = fmaf(xv, w4.z, acc[r][2]);
      acc[r][3] = fmaf(xv, w4.w, acc[r][3]);
    }
  }
#pragma unroll
  for (int r = 0; r < 4; ++r) {
    int row = rb + tr * 4 + r;
    if (row < n)
      *(float4*)(y + (size_t)row * 128 + j0) =
          make_float4(acc[r][0], acc[r][1], acc[r][2], acc[r][3]);
  }
}

extern "C" void kernel_launch(void* const* d_in, const int* in_sizes, int n_in,
                              void* d_out, int out_size, void* d_ws, size_t ws_size,
                              hipStream_t stream) {
  const int* labels = (const int*)d_in[0];
  const int* edge_index = (const int*)d_in[1];
  const float* weight = (const float*)d_in[2];
  const float* emb = (const float*)d_in[3];
  const float* W1 = (const float*)d_in[4];
  const float* b1 = (const float*)d_in[5];
  const float* W2 = (const float*)d_in[6];
  const float* b2 = (const float*)d_in[7];

  int n = in_sizes[0];
  int e = in_sizes[1] / 2;
  int vocab = in_sizes[3] / 128;
  const int* srcp = edge_index;
  const int* dstp = edge_index + e;

  int nb = (n + 63) >> 6;                 // dst buckets (782)
  int chunk = (e + CHUNKS - 1) / CHUNKS;  // 6250
  int bact = (e + chunk - 1) / chunk;
  int tblocks = (vocab + 7) / 8;          // temb blocks (125)

  float* ws = (float*)d_ws;
  size_t o = 0;
  auto alloc_f = [&](size_t c) { float* p = ws + o; o += (c + 255) & ~(size_t)255; return p; };
  int*      hist  = (int*)alloc_f((size_t)nb * CHUNKS);
  int*      off   = (int*)alloc_f((size_t)nb * CHUNKS);
  int*      tot   = (int*)alloc_f(nb);
  int*      ebase = (int*)alloc_f(nb + 1);
  int2*     brec  = (int2*)alloc_f((size_t)e * 2);
  int*      rs    = (int*)alloc_f(n + 1);
  int2*     csr   = (int2*)alloc_f((size_t)e * 2);
  float*    dinv  = alloc_f(n);
  __half*   temb  = (__half*)alloc_f((size_t)vocab * 64);  // vocab*128 halves
  unsigned* out8  = (unsigned*)alloc_f((size_t)n * 32);    // n*128 fp8
  (void)ws_size;

  dim3 b256(256);
  dim3 b1024(1024);
  int gagg = (int)(((size_t)n * 64 + 255) / 256);

  hist_temb_kernel<<<bact + tblocks, b1024, 0, stream>>>(dstp, hist, e, chunk, nb,
                                                         bact, emb, W1, temb, vocab);
  colscan_kernel<<<(nb * 64 + 255) / 256, b256, 0, stream>>>(hist, off, tot, nb, bact);
  ebase_kernel<<<1, b1024, 0, stream>>>(tot, ebase, nb);
  scatter_kernel<<<bact, b1024, 0, stream>>>(srcp, dstp, weight, labels, off, ebase,
                                             brec, e, chunk, nb);
  bsort_kernel<<<nb, b256, 0, stream>>>(brec, ebase, csr, rs, dinv, n);
  // layer 1: out8 = fp8(64*relu(A_hat temb[labels] + b1))
  agg1_kernel<<<gagg, b256, 0, stream>>>(rs, csr, dinv, labels, temb, b1, out8, n);
  // layer 2: d_out = (A_hat out1) @ W2 + b2   (agg first, then in-place GEMM)
  agg2_kernel<<<gagg, b256, 0, stream>>>(rs, csr, dinv, out8, (float*)d_out, n);
  gemm_bias_kernel<<<(n + 31) / 32, b256, 0, stream>>>((float*)d_out, W2, b2, n);
}

// Round 19
// 165.184 us; speedup vs baseline: 1.1101x; 1.0023x over previous
//
#include <hip/hip_runtime.h>
#include <hip/hip_fp16.h>

// ---------------------------------------------------------------------------
// 2-layer GCN on MI355X.  (R19 = R18/R14 base + DUAL-NODE agg waves.)
//   GCNConv(x) = A_hat (x W) + b = (A_hat x) W + b, and emb[labels]@W1 =
//   (emb@W1)[labels] -> layer 1 gathers from a 256KB fp16 L2-resident
//   per-label table; layer 2 aggregates first, then in-place GEMM on d_out.
// CSR build (zero global atomics): K1 hist (+fused temb) / K2 colscan /
// K2b ebase / K3 scatter (labels packed in csr.x) / K4 bsort (+dinv fold).
// Aggs: DUAL-NODE pair-gather -- each wave owns nodes 2g and 2g+1 with
// independent accumulator/record state; inner loop interleaves 4-pair
// sub-blocks {A-loads, B-loads, A-FMAs, B-FMAs} so one node's gathers are
// in flight while the other's FMAs retire (2x per-wave ILP; measured 42%
// VALUBusy / 56% occupancy says stalls dominate and TLP isn't enough).
// OOB edges self-nullify (v=0 lanes) -> no tail code. Epilogue: half-0
// lanes write node A, half-1 node B. out1 fp8 E4M3 x64 (agg2's byte lever).
// ---------------------------------------------------------------------------

#define CHUNKS 256  // chunk = ceil(e/256) = 6250 for e=1.6M
#define BSTAGE 2816 // bucket stage entries (avg bucket = 2048)

typedef float floatx2 __attribute__((ext_vector_type(2)));

// K1: blocks [0,bact): per-chunk histogram of dst-buckets.
//     blocks [bact, bact+ceil(vocab/8)): temb = emb @ W1 (8 rows/block, fp16).
__global__ __launch_bounds__(1024) void hist_temb_kernel(
    const int* __restrict__ dst, int* __restrict__ hist, int e, int chunk,
    int nb, int bact, const float* __restrict__ emb,
    const float* __restrict__ W1, __half* __restrict__ temb, int vocab) {
  __shared__ unsigned lh[1024];
  __shared__ float xs[8][128];
  int b = blockIdx.x, t = threadIdx.x;
  if (b < bact) {
    lh[t] = 0;
    __syncthreads();
    int start = b * chunk, end = min(e, start + chunk);
    for (int i = start + t; i < end; i += 1024) atomicAdd(&lh[dst[i] >> 6], 1u);
    __syncthreads();
    if (t < nb) hist[(size_t)t * CHUNKS + b] = (int)lh[t];
  } else {
    int r = (b - bact) * 8 + (t >> 7);
    int j = t & 127;
    if (r < vocab) xs[t >> 7][j] = emb[r * 128 + j];
    __syncthreads();
    if (r < vocab) {
      float acc = 0.f;
#pragma unroll 8
      for (int k = 0; k < 128; ++k) acc = fmaf(xs[t >> 7][k], W1[k * 128 + j], acc);
      temb[r * 128 + j] = __float2half_rn(acc);
    }
  }
}

// K2: one wave per bucket k: exclusive scan of hist[k][*] over chunks.
__global__ __launch_bounds__(256) void colscan_kernel(const int* __restrict__ hist,
                                                      int* __restrict__ off,
                                                      int* __restrict__ tot,
                                                      int nb, int bact) {
  int k = (blockIdx.x * 256 + threadIdx.x) >> 6;
  int lane = threadIdx.x & 63;
  if (k >= nb) return;
  int carry = 0;
  for (int r = 0; r < CHUNKS / 64; ++r) {
    int b = r * 64 + lane;
    int h = (b < bact) ? hist[(size_t)k * CHUNKS + b] : 0;
    int x = h;
#pragma unroll
    for (int d = 1; d < 64; d <<= 1) {
      int tt = __shfl_up(x, d, 64);
      if (lane >= d) x += tt;
    }
    if (b < bact) off[(size_t)k * CHUNKS + b] = carry + x - h;
    carry += __shfl(x, 63, 64);
  }
  if (lane == 0) tot[k] = carry;
}

// K2b: single block: exclusive scan of tot[nb] -> ebase[nb+1].
__global__ __launch_bounds__(1024) void ebase_kernel(const int* __restrict__ tot,
                                                     int* __restrict__ ebase, int nb) {
  __shared__ int wsum[16];
  int t = threadIdx.x, lane = t & 63, wv = t >> 6;
  int v = (t < nb) ? tot[t] : 0;
  int x = v;
#pragma unroll
  for (int d = 1; d < 64; d <<= 1) {
    int tt = __shfl_up(x, d, 64);
    if (lane >= d) x += tt;
  }
  if (lane == 63) wsum[wv] = x;
  __syncthreads();
  int o = 0;
#pragma unroll
  for (int w = 0; w < 16; ++w) o += (w < wv) ? wsum[w] : 0;
  int excl = x - v + o;
  if (t < nb) ebase[t] = excl;
  if (t == nb - 1) ebase[nb] = excl + v;
}

// K3: scatter edges into bucket-grouped records (LDS rank, no global atomics).
__global__ __launch_bounds__(1024) void scatter_kernel(
    const int* __restrict__ src, const int* __restrict__ dst,
    const float* __restrict__ w, const int* __restrict__ labels,
    const int* __restrict__ off, const int* __restrict__ ebase,
    int2* __restrict__ brec, int e, int chunk, int nb) {
  __shared__ unsigned bincnt[1024];
  __shared__ int gbase[1024];
  int b = blockIdx.x, t = threadIdx.x;
  bincnt[t] = 0;
  if (t < nb) gbase[t] = ebase[t] + off[(size_t)t * CHUNKS + b];
  __syncthreads();
  int start = b * chunk, end = min(e, start + chunk);
  int s[7], d[7], lb[7], ps[7];
  float wv[7];
#pragma unroll
  for (int u = 0; u < 7; ++u) {
    int i = start + u * 1024 + t;
    bool ok = i < end;
    s[u] = ok ? src[i] : 0;
    d[u] = ok ? dst[i] : 0;
    wv[u] = ok ? w[i] : 0.f;
  }
#pragma unroll
  for (int u = 0; u < 7; ++u) lb[u] = labels[s[u]];
#pragma unroll
  for (int u = 0; u < 7; ++u) ps[u] = gbase[d[u] >> 6];
#pragma unroll
  for (int u = 0; u < 7; ++u) {
    int i = start + u * 1024 + t;
    if (i < end) {
      int k = d[u] >> 6;
      unsigned lr = atomicAdd(&bincnt[k], 1u);
      unsigned rx = (unsigned)s[u] | ((unsigned)(d[u] & 63) << 16) |
                    ((unsigned)lb[u] << 22);
      brec[ps[u] + (int)lr] = make_int2((int)rx, __float_as_int(wv[u]));
    }
  }
}

// K4: per-bucket 64-bin sort: brec -> csr (src|label<<16, w), + rs[] + dinv.
__global__ __launch_bounds__(256) void bsort_kernel(const int2* __restrict__ brec,
                                                    const int* __restrict__ ebase,
                                                    int2* __restrict__ csr,
                                                    int* __restrict__ rs,
                                                    float* __restrict__ dinv, int n) {
  __shared__ int2 stage[BSTAGE];
  __shared__ unsigned h64[2][64];
  __shared__ unsigned cur[2][64];
  __shared__ float rsum[2][64];
  int k = blockIdx.x, t = threadIdx.x;
  int p = t >> 7;
  int e0 = ebase[k], e1 = ebase[k + 1], cnt = e1 - e0;
  if (t < 128) { h64[t >> 6][t & 63] = 0; rsum[t >> 6][t & 63] = 0.f; }
  __syncthreads();
  bool fits = (cnt <= BSTAGE);
  for (int i = t; i < cnt; i += 256) {
    int2 r = brec[e0 + i];
    if (fits) stage[i] = r;
    unsigned dl = ((unsigned)r.x >> 16) & 63u;
    atomicAdd(&h64[p][dl], 1u);
    atomicAdd(&rsum[p][dl], __int_as_float(r.y));
  }
  __syncthreads();
  if (t < 64) {
    int h0 = (int)h64[0][t];
    int hv = h0 + (int)h64[1][t];
    int x = hv;
#pragma unroll
    for (int d = 1; d < 64; d <<= 1) {
      int tt = __shfl_up(x, d, 64);
      if (t >= d) x += tt;
    }
    int ex = x - hv;
    cur[0][t] = (unsigned)(e0 + ex);
    cur[1][t] = (unsigned)(e0 + ex + h0);
    int v = k * 64 + t;
    if (v <= n) rs[v] = e0 + ex;
    if (v < n) dinv[v] = rsqrtf(1.0f + rsum[0][t] + rsum[1][t]);
  }
  __syncthreads();
  for (int i = t; i < cnt; i += 256) {
    int2 r = fits ? stage[i] : brec[e0 + i];
    unsigned rx = (unsigned)r.x;
    int dl = (int)((rx >> 16) & 63u);
    int pos = (int)atomicAdd(&cur[p][dl], 1u);
    csr[pos] = make_int2((int)((rx & 0xffffu) | ((rx >> 22) << 16)), r.y);
  }
}

// unpack 4 halves (loaded as float2, 8B) -> two float2
__device__ __forceinline__ void unpack4(float2 raw, float2& a, float2& b) {
  union { float f; __half2 h; } u0, u1;
  u0.f = raw.x;
  u1.f = raw.y;
  a = __half22float2(u0.h);
  b = __half22float2(u1.h);
}

// Layer 1, dual-node: out8 = fp8(64*relu(A_hat temb[labels] + b1)).
__global__ __launch_bounds__(256) void agg1_kernel(
    const int* __restrict__ rs, const int2* __restrict__ csr,
    const float* __restrict__ dinv, const int* __restrict__ labels,
    const __half* __restrict__ temb, const float* __restrict__ b1,
    unsigned* __restrict__ out8, int n) {
  int gw = (blockIdx.x * blockDim.x + threadIdx.x) >> 6;
  int widA = gw * 2;
  if (widA >= n) return;
  int widB = widA + 1;
  bool hasB = widB < n;
  int lane = threadIdx.x & 63;
  int half = lane >> 5, fl = lane & 31;
  unsigned flo = (unsigned)(fl << 3);
  const char* tb = (const char*)temb;
  float diA = dinv[widA];
  float diB = hasB ? dinv[widB] : 0.f;
  float aA0, aA1, aA2, aA3;
  float aB0 = 0.f, aB1 = 0.f, aB2 = 0.f, aB3 = 0.f;
  {
    float2 raw = *(const float2*)(tb + ((unsigned)labels[widA] << 8) + flo);
    float2 a, b;
    unpack4(raw, a, b);
    float ss = half ? 0.f : diA;  // A's self term on half 0
    aA0 = a.x * ss; aA1 = a.y * ss; aA2 = b.x * ss; aA3 = b.y * ss;
  }
  if (hasB) {
    float2 raw = *(const float2*)(tb + ((unsigned)labels[widB] << 8) + flo);
    float2 a, b;
    unpack4(raw, a, b);
    float ss = half ? diB : 0.f;  // B's self term on half 1
    aB0 = a.x * ss; aB1 = a.y * ss; aB2 = b.x * ss; aB3 = b.y * ss;
  }
  int baseA = rs[widA], r1A = rs[widA + 1];
  int baseB = hasB ? rs[widB] : 0, r1B = hasB ? rs[widB + 1] : 0;
  int sA = 0, sB = 0;
  float vA = 0.f, vB = 0.f;
  if (baseA + lane < r1A) {
    int2 c = csr[baseA + lane];
    sA = c.x;
    vA = __int_as_float(c.y) * dinv[c.x & 0xffff];
  }
  if (baseB + lane < r1B) {
    int2 c = csr[baseB + lane];
    sB = c.x;
    vB = __int_as_float(c.y) * dinv[c.x & 0xffff];
  }
  while (baseA < r1A || baseB < r1B) {
    int nsA = 0, nsB = 0;
    float nvA = 0.f, nvB = 0.f;
    if (baseA + 64 + lane < r1A) {
      int2 c = csr[baseA + 64 + lane];
      nsA = c.x;
      nvA = __int_as_float(c.y) * dinv[c.x & 0xffff];
    }
    if (baseB + 64 + lane < r1B) {
      int2 c = csr[baseB + 64 + lane];
      nsB = c.x;
      nvB = __int_as_float(c.y) * dinv[c.x & 0xffff];
    }
    int nbA = min(64, max(0, r1A - baseA));
    int nbB = min(64, max(0, r1B - baseB));
    int nbmax = max(nbA, nbB);
    for (int j = 0; j < nbmax; j += 8) {
      bool doA = j < nbA, doB = j < nbB;
      float2 rA[4], rB[4];
      float wjA[4], wjB[4];
      if (doA) {
#pragma unroll
        for (int u = 0; u < 4; ++u) {
          int jj = j + 2 * u + half;  // OOB edges carry v=0 -> contribute 0
          int sj = __shfl(sA, jj, 64);
          wjA[u] = __shfl(vA, jj, 64);
          rA[u] = *(const float2*)(tb + ((((unsigned)sj) >> 16) << 8) + flo);
        }
      }
      if (doB) {
#pragma unroll
        for (int u = 0; u < 4; ++u) {
          int jj = j + 2 * u + half;
          int sj = __shfl(sB, jj, 64);
          wjB[u] = __shfl(vB, jj, 64);
          rB[u] = *(const float2*)(tb + ((((unsigned)sj) >> 16) << 8) + flo);
        }
      }
      if (doA) {
#pragma unroll
        for (int u = 0; u < 4; ++u) {
          float2 a, b;
          unpack4(rA[u], a, b);
          aA0 = fmaf(a.x, wjA[u], aA0); aA1 = fmaf(a.y, wjA[u], aA1);
          aA2 = fmaf(b.x, wjA[u], aA2); aA3 = fmaf(b.y, wjA[u], aA3);
        }
      }
      if (doB) {
#pragma unroll
        for (int u = 0; u < 4; ++u) {
          float2 a, b;
          unpack4(rB[u], a, b);
          aB0 = fmaf(a.x, wjB[u], aB0); aB1 = fmaf(a.y, wjB[u], aB1);
          aB2 = fmaf(b.x, wjB[u], aB2); aB3 = fmaf(b.y, wjB[u], aB3);
        }
      }
    }
    baseA += 64;
    baseB += 64;
    sA = nsA; vA = nvA; sB = nsB; vB = nvB;
  }
  aA0 += __shfl_xor(aA0, 32, 64); aA1 += __shfl_xor(aA1, 32, 64);
  aA2 += __shfl_xor(aA2, 32, 64); aA3 += __shfl_xor(aA3, 32, 64);
  aB0 += __shfl_xor(aB0, 32, 64); aB1 += __shfl_xor(aB1, 32, 64);
  aB2 += __shfl_xor(aB2, 32, 64); aB3 += __shfl_xor(aB3, 32, 64);
  float4 b4 = ((const float4*)b1)[fl];
  if (half == 0) {
    float o0 = fmaxf(fmaf(aA0, diA, b4.x), 0.f) * 64.f;
    float o1 = fmaxf(fmaf(aA1, diA, b4.y), 0.f) * 64.f;
    float o2 = fmaxf(fmaf(aA2, diA, b4.z), 0.f) * 64.f;
    float o3 = fmaxf(fmaf(aA3, diA, b4.w), 0.f) * 64.f;
    int pk = __builtin_amdgcn_cvt_pk_fp8_f32(o0, o1, 0, false);
    pk = __builtin_amdgcn_cvt_pk_fp8_f32(o2, o3, pk, true);
    out8[(size_t)widA * 32 + fl] = (unsigned)pk;
  } else if (hasB) {
    float o0 = fmaxf(fmaf(aB0, diB, b4.x), 0.f) * 64.f;
    float o1 = fmaxf(fmaf(aB1, diB, b4.y), 0.f) * 64.f;
    float o2 = fmaxf(fmaf(aB2, diB, b4.z), 0.f) * 64.f;
    float o3 = fmaxf(fmaf(aB3, diB, b4.w), 0.f) * 64.f;
    int pk = __builtin_amdgcn_cvt_pk_fp8_f32(o0, o1, 0, false);
    pk = __builtin_amdgcn_cvt_pk_fp8_f32(o2, o3, pk, true);
    out8[(size_t)widB * 32 + fl] = (unsigned)pk;
  }
}

// Layer 2, dual-node: out = A_hat h (fp8 source, f32 out).
__global__ __launch_bounds__(256) void agg2_kernel(
    const int* __restrict__ rs, const int2* __restrict__ csr,
    const float* __restrict__ dinv, const unsigned* __restrict__ h8,
    float* __restrict__ out, int n) {
  int gw = (blockIdx.x * blockDim.x + threadIdx.x) >> 6;
  int widA = gw * 2;
  if (widA >= n) return;
  int widB = widA + 1;
  bool hasB = widB < n;
  int lane = threadIdx.x & 63;
  int half = lane >> 5, fl = lane & 31;
  unsigned flo = (unsigned)(fl << 2);
  const char* hb = (const char*)h8;
  float diA = dinv[widA];
  float diB = hasB ? dinv[widB] : 0.f;
  float aA0, aA1, aA2, aA3;
  float aB0 = 0.f, aB1 = 0.f, aB2 = 0.f, aB3 = 0.f;
  {
    unsigned r8 = *(const unsigned*)(hb + ((unsigned)widA << 7) + flo);
    floatx2 a = __builtin_amdgcn_cvt_pk_f32_fp8((int)r8, false);
    floatx2 b = __builtin_amdgcn_cvt_pk_f32_fp8((int)r8, true);
    float ss = half ? 0.f : diA;
    aA0 = a[0] * ss; aA1 = a[1] * ss; aA2 = b[0] * ss; aA3 = b[1] * ss;
  }
  if (hasB) {
    unsigned r8 = *(const unsigned*)(hb + ((unsigned)widB << 7) + flo);
    floatx2 a = __builtin_amdgcn_cvt_pk_f32_fp8((int)r8, false);
    floatx2 b = __builtin_amdgcn_cvt_pk_f32_fp8((int)r8, true);
    float ss = half ? diB : 0.f;
    aB0 = a[0] * ss; aB1 = a[1] * ss; aB2 = b[0] * ss; aB3 = b[1] * ss;
  }
  int baseA = rs[widA], r1A = rs[widA + 1];
  int baseB = hasB ? rs[widB] : 0, r1B = hasB ? rs[widB + 1] : 0;
  int sA = 0, sB = 0;
  float vA = 0.f, vB = 0.f;
  if (baseA + lane < r1A) {
    int2 c = csr[baseA + lane];
    sA = c.x;
    vA = __int_as_float(c.y) * dinv[c.x & 0xffff];
  }
  if (baseB + lane < r1B) {
    int2 c = csr[baseB + lane];
    sB = c.x;
    vB = __int_as_float(c.y) * dinv[c.x & 0xffff];
  }
  while (baseA < r1A || baseB < r1B) {
    int nsA = 0, nsB = 0;
    float nvA = 0.f, nvB = 0.f;
    if (baseA + 64 + lane < r1A) {
      int2 c = csr[baseA + 64 + lane];
      nsA = c.x;
      nvA = __int_as_float(c.y) * dinv[c.x & 0xffff];
    }
    if (baseB + 64 + lane < r1B) {
      int2 c = csr[baseB + 64 + lane];
      nsB = c.x;
      nvB = __int_as_float(c.y) * dinv[c.x & 0xffff];
    }
    int nbA = min(64, max(0, r1A - baseA));
    int nbB = min(64, max(0, r1B - baseB));
    int nbmax = max(nbA, nbB);
    for (int j = 0; j < nbmax; j += 8) {
      bool doA = j < nbA, doB = j < nbB;
      unsigned rA[4], rB[4];
      float wjA[4], wjB[4];
      if (doA) {
#pragma unroll
        for (int u = 0; u < 4; ++u) {
          int jj = j + 2 * u + half;
          int sj = __shfl(sA, jj, 64);
          wjA[u] = __shfl(vA, jj, 64);
          rA[u] = *(const unsigned*)(hb + ((((unsigned)sj) & 0xffffu) << 7) + flo);
        }
      }
      if (doB) {
#pragma unroll
        for (int u = 0; u < 4; ++u) {
          int jj = j + 2 * u + half;
          int sj = __shfl(sB, jj, 64);
          wjB[u] = __shfl(vB, jj, 64);
          rB[u] = *(const unsigned*)(hb + ((((unsigned)sj) & 0xffffu) << 7) + flo);
        }
      }
      if (doA) {
#pragma unroll
        for (int u = 0; u < 4; ++u) {
          floatx2 a = __builtin_amdgcn_cvt_pk_f32_fp8((int)rA[u], false);
          floatx2 b = __builtin_amdgcn_cvt_pk_f32_fp8((int)rA[u], true);
          aA0 = fmaf(a[0], wjA[u], aA0); aA1 = fmaf(a[1], wjA[u], aA1);
          aA2 = fmaf(b[0], wjA[u], aA2); aA3 = fmaf(b[1], wjA[u], aA3);
        }
      }
      if (doB) {
#pragma unroll
        for (int u = 0; u < 4; ++u) {
          floatx2 a = __builtin_amdgcn_cvt_pk_f32_fp8((int)rB[u], false);
          floatx2 b = __builtin_amdgcn_cvt_pk_f32_fp8((int)rB[u], true);
          aB0 = fmaf(a[0], wjB[u], aB0); aB1 = fmaf(a[1], wjB[u], aB1);
          aB2 = fmaf(b[0], wjB[u], aB2); aB3 = fmaf(b[1], wjB[u], aB3);
        }
      }
    }
    baseA += 64;
    baseB += 64;
    sA = nsA; vA = nvA; sB = nsB; vB = nvB;
  }
  aA0 += __shfl_xor(aA0, 32, 64); aA1 += __shfl_xor(aA1, 32, 64);
  aA2 += __shfl_xor(aA2, 32, 64); aA3 += __shfl_xor(aA3, 32, 64);
  aB0 += __shfl_xor(aB0, 32, 64); aB1 += __shfl_xor(aB1, 32, 64);
  aB2 += __shfl_xor(aB2, 32, 64); aB3 += __shfl_xor(aB3, 32, 64);
  if (half == 0) {
    float sc = diA * 0.015625f;  // /64 de-scale
    ((float4*)(out + (size_t)widA * 128))[fl] =
        make_float4(aA0 * sc, aA1 * sc, aA2 * sc, aA3 * sc);
  } else if (hasB) {
    float sc = diB * 0.015625f;
    ((float4*)(out + (size_t)widB * 128))[fl] =
        make_float4(aB0 * sc, aB1 * sc, aB2 * sc, aB3 * sc);
  }
}

// In-place: y[rb..rb+31] = y[rb..rb+31] @ W + b.
__global__ __launch_bounds__(256) void gemm_bias_kernel(float* __restrict__ y,
                                                        const float* __restrict__ W,
                                                        const float* __restrict__ bias,
                                                        int n) {
  __shared__ float xs[32][128];
  int tid = threadIdx.x;
  int tc = tid & 31;
  int tr = tid >> 5;
  int rb = blockIdx.x * 32;
  {
    const float4* xg = (const float4*)(y + (size_t)rb * 128);
    float4* xls = (float4*)&xs[0][0];
#pragma unroll
    for (int i = 0; i < 4; ++i) {
      int idx = tid + i * 256;
      int row = rb + (idx >> 5);
      float4 val = (row < n) ? xg[idx] : make_float4(0.f, 0.f, 0.f, 0.f);
      xls[idx] = val;
    }
  }
  __syncthreads();
  int j0 = tc * 4;
  float4 b4 = *(const float4*)(bias + j0);
  float acc[4][4];
#pragma unroll
  for (int r = 0; r < 4; ++r) {
    acc[r][0] = b4.x; acc[r][1] = b4.y; acc[r][2] = b4.z; acc[r][3] = b4.w;
  }
#pragma unroll 4
  for (int k = 0; k < 128; ++k) {
    float4 w4 = *(const float4*)(W + k * 128 + j0);
#pragma unroll
    for (int r = 0; r < 4; ++r) {
      float xv = xs[tr * 4 + r][k];
      acc[r][0] = fmaf(xv, w4.x, acc[r][0]);
      acc[r][1] = fmaf(xv, w4.y, acc[r][1]);
      acc[r][2] = fmaf(xv, w4.z, acc[r][2]);
      acc[r][3] = fmaf(xv, w4.w, acc[r][3]);
    }
  }
#pragma unroll
  for (int r = 0; r < 4; ++r) {
    int row = rb + tr * 4 + r;
    if (row < n)
      *(float4*)(y + (size_t)row * 128 + j0) =
          make_float4(acc[r][0], acc[r][1], acc[r][2], acc[r][3]);
  }
}

extern "C" void kernel_launch(void* const* d_in, const int* in_sizes, int n_in,
                              void* d_out, int out_size, void* d_ws, size_t ws_size,
                              hipStream_t stream) {
  const int* labels = (const int*)d_in[0];
  const int* edge_index = (const int*)d_in[1];
  const float* weight = (const float*)d_in[2];
  const float* emb = (const float*)d_in[3];
  const float* W1 = (const float*)d_in[4];
  const float* b1 = (const float*)d_in[5];
  const float* W2 = (const float*)d_in[6];
  const float* b2 = (const float*)d_in[7];

  int n = in_sizes[0];
  int e = in_sizes[1] / 2;
  int vocab = in_sizes[3] / 128;
  const int* srcp = edge_index;
  const int* dstp = edge_index + e;

  int nb = (n + 63) >> 6;                 // dst buckets (782)
  int chunk = (e + CHUNKS - 1) / CHUNKS;  // 6250
  int bact = (e + chunk - 1) / chunk;
  int tblocks = (vocab + 7) / 8;          // temb blocks (125)

  float* ws = (float*)d_ws;
  size_t o = 0;
  auto alloc_f = [&](size_t c) { float* p = ws + o; o += (c + 255) & ~(size_t)255; return p; };
  int*      hist  = (int*)alloc_f((size_t)nb * CHUNKS);
  int*      off   = (int*)alloc_f((size_t)nb * CHUNKS);
  int*      tot   = (int*)alloc_f(nb);
  int*      ebase = (int*)alloc_f(nb + 1);
  int2*     brec  = (int2*)alloc_f((size_t)e * 2);
  int*      rs    = (int*)alloc_f(n + 1);
  int2*     csr   = (int2*)alloc_f((size_t)e * 2);
  float*    dinv  = alloc_f(n);
  __half*   temb  = (__half*)alloc_f((size_t)vocab * 64);  // vocab*128 halves
  unsigned* out8  = (unsigned*)alloc_f((size_t)n * 32);    // n*128 fp8
  (void)ws_size;

  dim3 b256(256);
  dim3 b1024(1024);
  int nwaves = (n + 1) / 2;  // dual-node waves
  int gagg = (int)(((size_t)nwaves * 64 + 255) / 256);

  hist_temb_kernel<<<bact + tblocks, b1024, 0, stream>>>(dstp, hist, e, chunk, nb,
                                                         bact, emb, W1, temb, vocab);
  colscan_kernel<<<(nb * 64 + 255) / 256, b256, 0, stream>>>(hist, off, tot, nb, bact);
  ebase_kernel<<<1, b1024, 0, stream>>>(tot, ebase, nb);
  scatter_kernel<<<bact, b1024, 0, stream>>>(srcp, dstp, weight, labels, off, ebase,
                                             brec, e, chunk, nb);
  bsort_kernel<<<nb, b256, 0, stream>>>(brec, ebase, csr, rs, dinv, n);
  // layer 1: out8 = fp8(64*relu(A_hat temb[labels] + b1))
  agg1_kernel<<<gagg, b256, 0, stream>>>(rs, csr, dinv, labels, temb, b1, out8, n);
  // layer 2: d_out = (A_hat out1) @ W2 + b2   (agg first, then in-place GEMM)
  agg2_kernel<<<gagg, b256, 0, stream>>>(rs, csr, dinv, out8, (float*)d_out, n);
  gemm_bias_kernel<<<(n + 31) / 32, b256, 0, stream>>>((float*)d_out, W2, b2, n);
}